// Round 1
// baseline (1285.237 us; speedup 1.0000x reference)
//
#include <hip/hip_runtime.h>
#include <stdint.h>

// ---------------------------------------------------------------------------
// Threefry-2x32 (JAX/Random123 schedule), usable on host (key folding) + device
// ---------------------------------------------------------------------------
__host__ __device__ inline uint32_t rotl32(uint32_t v, int d) {
  return (v << d) | (v >> (32 - d));
}

__host__ __device__ inline void tf2x32(uint32_t k0, uint32_t k1,
                                       uint32_t x0, uint32_t x1,
                                       uint32_t& o0, uint32_t& o1) {
  uint32_t ks0 = k0, ks1 = k1, ks2 = k0 ^ k1 ^ 0x1BD11BDAu;
  x0 += ks0; x1 += ks1;
#define TF_R(r) { x0 += x1; x1 = rotl32(x1, (r)); x1 ^= x0; }
  TF_R(13) TF_R(15) TF_R(26) TF_R(6)
  x0 += ks1; x1 += ks2 + 1u;
  TF_R(17) TF_R(29) TF_R(16) TF_R(24)
  x0 += ks2; x1 += ks0 + 2u;
  TF_R(13) TF_R(15) TF_R(26) TF_R(6)
  x0 += ks0; x1 += ks1 + 3u;
  TF_R(17) TF_R(29) TF_R(16) TF_R(24)
  x0 += ks1; x1 += ks2 + 4u;
  TF_R(13) TF_R(15) TF_R(26) TF_R(6)
  x0 += ks2; x1 += ks0 + 5u;
#undef TF_R
  o0 = x0; o1 = x1;
}

// XLA's fp32 erf_inv (Giles polynomial) — matches the reference's lax.erf_inv
__device__ inline float erfinv_xla(float x) {
  float w = -log1pf(-x * x);
  float p;
  if (w < 5.0f) {
    w = w - 2.5f;
    p = 2.81022636e-08f;
    p = fmaf(p, w, 3.43273939e-07f);
    p = fmaf(p, w, -3.5233877e-06f);
    p = fmaf(p, w, -4.39150654e-06f);
    p = fmaf(p, w, 0.00021858087f);
    p = fmaf(p, w, -0.00125372503f);
    p = fmaf(p, w, -0.00417768164f);
    p = fmaf(p, w, 0.246640727f);
    p = fmaf(p, w, 1.50140941f);
  } else {
    w = sqrtf(w) - 3.0f;
    p = -0.000200214257f;
    p = fmaf(p, w, 0.000100950558f);
    p = fmaf(p, w, 0.00134934322f);
    p = fmaf(p, w, -0.00367342844f);
    p = fmaf(p, w, 0.00573950773f);
    p = fmaf(p, w, -0.0076224613f);
    p = fmaf(p, w, 0.00943887047f);
    p = fmaf(p, w, 1.00167406f);
    p = fmaf(p, w, 2.83297682f);
  }
  return p * x;
}

// JAX random.normal bit mapping: u in [nextafter(-1,0), 1), X = sqrt(2)*erfinv(u)
__device__ inline float bits_to_normal(uint32_t bits) {
  uint32_t fb = (bits >> 9) | 0x3F800000u;
  float f = __uint_as_float(fb) - 1.0f;        // [0,1)
  const float lo = -0.99999994f;               // nextafter(-1,0) fp32
  float u = fmaf(f, 1.0f - lo, lo);
  u = fmaxf(lo, u);
  return 1.41421356f * erfinv_xla(u);
}

// branchless sorted-descending top-5 insert
__device__ inline void ins5(float (&t)[5], float v) {
  float a = v;
#pragma unroll
  for (int q = 0; q < 5; ++q) {
    float hi = fmaxf(t[q], a);
    a = fminf(t[q], a);
    t[q] = hi;
  }
}

#define XS_STRIDE 129            // pad K<=128 rows to kill bank conflicts
#define POOL_OFF  (2 * 32 * XS_STRIDE)   // 8256 floats
#define POOL_SZ   5120           // floats: max(P chunk 2*16*128=4096, scratch 2*32*16*5=5120)

// ---------------------------------------------------------------------------
// Per-combo worker. Block handles rows (rp, rp+512) within combo (threefry pair).
// ---------------------------------------------------------------------------
template <int K>
__device__ void process_combo(const float* __restrict__ Pp,
                              const float* __restrict__ yp,
                              const float* __restrict__ yt,
                              float* __restrict__ accum,
                              int m, int ofs, uint32_t key0, uint32_t key1,
                              int rp, float* sm, float* hm_all, float* maxhm) {
  constexpr int RC = 16;          // P rows per chunk
  constexpr int NCPT = K / 16;    // output cols per thread
  constexpr int NV4 = K / 64;     // float4 col groups
  constexpr int REM = K - NV4 * 64;

  const int tid = threadIdx.x;
  const int tx = tid & 15, ty = tid >> 4;
  const int b0 = 4 * rp + ofs;
  const int b1 = 4 * (rp + 512) + ofs;
  const float* P0 = Pp + (size_t)b0 * 16384;
  const float* P1 = Pp + (size_t)b1 * 16384;
  const uint32_t half = 65536u * (uint32_t)K;   // 512*128*K

  float* Xs = sm;                 // [2][32][XS_STRIDE]
  float* pool = sm + POOL_OFF;    // P staging, later top-5 scratch

  if (tid < 2) maxhm[tid] = 0.0f;

  for (int tile = 0; tile < 4; ++tile) {
    const int s_base = tile * 32;

    // ---- Phase A: generate X for both rows (one threefry per element pair)
    for (int e = tid; e < 32 * K; e += 256) {
      int s_local = e / K;
      int j = e - s_local * K;
      uint32_t f = ((uint32_t)(rp * 128 + s_base + s_local)) * (uint32_t)K + (uint32_t)j;
      uint32_t o0, o1;
      tf2x32(key0, key1, f, f + half, o0, o1);
      Xs[(0 * 32 + s_local) * XS_STRIDE + j] = bits_to_normal(o0);
      Xs[(1 * 32 + s_local) * XS_STRIDE + j] = bits_to_normal(o1);
    }

    float acc[2][2][8];
#pragma unroll
    for (int r = 0; r < 2; ++r)
#pragma unroll
      for (int s = 0; s < 2; ++s)
#pragma unroll
        for (int c = 0; c < 8; ++c) acc[r][s][c] = 0.0f;

    __syncthreads();   // X visible (also covers maxhm init / prev-tile reuse)

    // ---- Phase B: Y = X @ P, P streamed in RC-row chunks
    for (int rb = 0; rb < K; rb += RC) {
      const int NF4 = 2 * RC * K / 4;
      for (int q = tid; q < NF4; q += 256) {
        int row = q / (RC * K / 4);
        int rem = q - row * (RC * K / 4);
        int rr = rem / (K / 4);
        int c4 = rem - rr * (K / 4);
        const float* src = (row == 0 ? P0 : P1) + (rb + rr) * 128 + c4 * 4;
        *(float4*)(pool + (row * RC + rr) * K + c4 * 4) = *(const float4*)src;
      }
      __syncthreads();

#pragma unroll
      for (int rr = 0; rr < RC; ++rr) {
        float xv[2][2];
#pragma unroll
        for (int row = 0; row < 2; ++row)
#pragma unroll
          for (int ss = 0; ss < 2; ++ss)
            xv[row][ss] = Xs[(row * 32 + ty * 2 + ss) * XS_STRIDE + rb + rr];

#pragma unroll
        for (int row = 0; row < 2; ++row) {
          const float* pr = pool + (row * RC + rr) * K;
          int ci = 0;
#pragma unroll
          for (int q = 0; q < NV4; ++q) {
            float4 pv = *(const float4*)(pr + q * 64 + 4 * tx);
#pragma unroll
            for (int ss = 0; ss < 2; ++ss) {
              acc[row][ss][ci + 0] = fmaf(xv[row][ss], pv.x, acc[row][ss][ci + 0]);
              acc[row][ss][ci + 1] = fmaf(xv[row][ss], pv.y, acc[row][ss][ci + 1]);
              acc[row][ss][ci + 2] = fmaf(xv[row][ss], pv.z, acc[row][ss][ci + 2]);
              acc[row][ss][ci + 3] = fmaf(xv[row][ss], pv.w, acc[row][ss][ci + 3]);
            }
            ci += 4;
          }
          if constexpr (REM >= 32) {
            float2 pv = *(const float2*)(pr + NV4 * 64 + 2 * tx);
#pragma unroll
            for (int ss = 0; ss < 2; ++ss) {
              acc[row][ss][ci + 0] = fmaf(xv[row][ss], pv.x, acc[row][ss][ci + 0]);
              acc[row][ss][ci + 1] = fmaf(xv[row][ss], pv.y, acc[row][ss][ci + 1]);
            }
            ci += 2;
          }
          if constexpr (REM == 16 || REM == 48) {
            float pv = pr[NV4 * 64 + (REM == 48 ? 32 : 0) + tx];
#pragma unroll
            for (int ss = 0; ss < 2; ++ss)
              acc[row][ss][ci] = fmaf(xv[row][ss], pv, acc[row][ss][ci]);
            ci += 1;
          }
        }
      }
      __syncthreads();
    }

    // ---- Phase C: per-thread partial top-5 over |Y| cols + |X| cols
#pragma unroll
    for (int row = 0; row < 2; ++row) {
#pragma unroll
      for (int ss = 0; ss < 2; ++ss) {
        float t5[5] = {-1e30f, -1e30f, -1e30f, -1e30f, -1e30f};
#pragma unroll
        for (int c = 0; c < NCPT; ++c) ins5(t5, fabsf(acc[row][ss][c]));
        const int s_local = ty * 2 + ss;
        const float* xrow = Xs + (row * 32 + s_local) * XS_STRIDE;
#pragma unroll
        for (int q = 0; q < NCPT; ++q) ins5(t5, fabsf(xrow[q * 16 + tx]));
        float* dst = pool + ((row * 32 + s_local) * 16 + tx) * 5;
#pragma unroll
        for (int q = 0; q < 5; ++q) dst[q] = t5[q];
      }
    }
    __syncthreads();

    // merge 16 partial top-5s -> hm per (row, sample)
    if (tid < 64) {
      int row = tid >> 5, s_local = tid & 31;
      const float* src = pool + (row * 32 + s_local) * 80;
      float t5[5] = {-1e30f, -1e30f, -1e30f, -1e30f, -1e30f};
      for (int q = 0; q < 80; ++q) ins5(t5, src[q]);
      float tm = (m == 2) ? t5[2] : ((m == 3) ? t5[3] : t5[4]);
      hm_all[tid] = t5[0] / (tm + 1e-9f);
    }
    __syncthreads();
    if (tid < 2) {
      float mx = maxhm[tid];
      for (int s = 0; s < 32; ++s) mx = fmaxf(mx, hm_all[tid * 32 + s]);
      maxhm[tid] = mx;
    }
    __syncthreads();
  }

  if (tid == 0) {
    float pen = fmaxf(maxhm[0] - yp[b0], 0.0f) + fmaxf(maxhm[1] - yp[b1], 0.0f);
    atomicAdd(&accum[0], pen);
    float d0 = log2f(fmaxf(yt[b0], 1e-9f)) - log2f(fmaxf(yp[b0], 1e-9f));
    float d1 = log2f(fmaxf(yt[b1], 1e-9f)) - log2f(fmaxf(yp[b1], 1e-9f));
    atomicAdd(&accum[1], fmaf(d0, d0, d1 * d1));
  }
}

struct ComboArgs {
  int m[4];
  int ofs[4];
  uint32_t k0[4];
  uint32_t k1[4];
};

__global__ __launch_bounds__(256)
void viol_kernel(const float* __restrict__ Pp, const float* __restrict__ yp,
                 const float* __restrict__ yt, float* __restrict__ accum,
                 ComboArgs ca) {
  __shared__ __align__(16) float sm[POOL_OFF + POOL_SZ];
  __shared__ float hm_all[64];
  __shared__ float maxhm[2];
  int i = blockIdx.x >> 9;
  int rp = blockIdx.x & 511;
  switch (i) {
    case 0: process_combo<80>(Pp, yp, yt, accum, ca.m[0], ca.ofs[0], ca.k0[0], ca.k1[0], rp, sm, hm_all, maxhm); break;
    case 1: process_combo<96>(Pp, yp, yt, accum, ca.m[1], ca.ofs[1], ca.k0[1], ca.k1[1], rp, sm, hm_all, maxhm); break;
    case 2: process_combo<112>(Pp, yp, yt, accum, ca.m[2], ca.ofs[2], ca.k0[2], ca.k1[2], rp, sm, hm_all, maxhm); break;
    default: process_combo<128>(Pp, yp, yt, accum, ca.m[3], ca.ofs[3], ca.k0[3], ca.k1[3], rp, sm, hm_all, maxhm); break;
  }
}

__global__ void finalize_kernel(const float* __restrict__ accum, float* __restrict__ out) {
  if (threadIdx.x == 0 && blockIdx.x == 0) {
    float viol = accum[0] / 4096.0f;
    float lm = accum[1] / 4096.0f;
    out[0] = fmaf(0.5f, viol, lm);
    out[1] = lm;
    out[2] = viol;
  }
}

extern "C" void kernel_launch(void* const* d_in, const int* in_sizes, int n_in,
                              void* d_out, int out_size, void* d_ws, size_t ws_size,
                              hipStream_t stream) {
  const float* y_pred   = (const float*)d_in[0];
  const float* y_true   = (const float*)d_in[1];
  const float* P_padded = (const float*)d_in[2];
  float* accum = (float*)d_ws;
  float* out = (float*)d_out;

  hipMemsetAsync(accum, 0, 2 * sizeof(float), stream);

  // combos sorted as np.unique: (160,80,2)<-b%4==3, (192,96,3)<-1, (224,112,4)<-2, (256,128,3)<-0
  ComboArgs ca;
  const int ms[4]  = {2, 3, 4, 3};
  const int ofs[4] = {3, 1, 2, 0};
  for (int i = 0; i < 4; ++i) {
    ca.m[i] = ms[i];
    ca.ofs[i] = ofs[i];
    uint32_t o0, o1;
    tf2x32(0u, 42u, 0u, (uint32_t)i, o0, o1);  // fold_in(key(42), i)
    ca.k0[i] = o0;
    ca.k1[i] = o1;
  }

  viol_kernel<<<2048, 256, 0, stream>>>(P_padded, y_pred, y_true, accum, ca);
  finalize_kernel<<<1, 64, 0, stream>>>(accum, out);
}

// Round 2
// 769.351 us; speedup vs baseline: 1.6705x; 1.6705x over previous
//
#include <hip/hip_runtime.h>
#include <stdint.h>

typedef short bf16x8 __attribute__((ext_vector_type(8)));
typedef float f32x4 __attribute__((ext_vector_type(4)));

// ---------------------------------------------------------------------------
// Threefry-2x32 (JAX/Random123 schedule)
// ---------------------------------------------------------------------------
__host__ __device__ inline uint32_t rotl32(uint32_t v, int d) {
  return (v << d) | (v >> (32 - d));
}

__host__ __device__ inline void tf2x32(uint32_t k0, uint32_t k1,
                                       uint32_t x0, uint32_t x1,
                                       uint32_t& o0, uint32_t& o1) {
  uint32_t ks0 = k0, ks1 = k1, ks2 = k0 ^ k1 ^ 0x1BD11BDAu;
  x0 += ks0; x1 += ks1;
#define TF_R(r) { x0 += x1; x1 = rotl32(x1, (r)); x1 ^= x0; }
  TF_R(13) TF_R(15) TF_R(26) TF_R(6)
  x0 += ks1; x1 += ks2 + 1u;
  TF_R(17) TF_R(29) TF_R(16) TF_R(24)
  x0 += ks2; x1 += ks0 + 2u;
  TF_R(13) TF_R(15) TF_R(26) TF_R(6)
  x0 += ks0; x1 += ks1 + 3u;
  TF_R(17) TF_R(29) TF_R(16) TF_R(24)
  x0 += ks1; x1 += ks2 + 4u;
  TF_R(13) TF_R(15) TF_R(26) TF_R(6)
  x0 += ks2; x1 += ks0 + 5u;
#undef TF_R
  o0 = x0; o1 = x1;
}

// XLA's fp32 erf_inv (Giles polynomial)
__device__ __forceinline__ float erfinv_xla(float x) {
  float w = -log1pf(-x * x);
  float p;
  if (w < 5.0f) {
    w = w - 2.5f;
    p = 2.81022636e-08f;
    p = fmaf(p, w, 3.43273939e-07f);
    p = fmaf(p, w, -3.5233877e-06f);
    p = fmaf(p, w, -4.39150654e-06f);
    p = fmaf(p, w, 0.00021858087f);
    p = fmaf(p, w, -0.00125372503f);
    p = fmaf(p, w, -0.00417768164f);
    p = fmaf(p, w, 0.246640727f);
    p = fmaf(p, w, 1.50140941f);
  } else {
    w = sqrtf(w) - 3.0f;
    p = -0.000200214257f;
    p = fmaf(p, w, 0.000100950558f);
    p = fmaf(p, w, 0.00134934322f);
    p = fmaf(p, w, -0.00367342844f);
    p = fmaf(p, w, 0.00573950773f);
    p = fmaf(p, w, -0.0076224613f);
    p = fmaf(p, w, 0.00943887047f);
    p = fmaf(p, w, 1.00167406f);
    p = fmaf(p, w, 2.83297682f);
  }
  return p * x;
}

__device__ __forceinline__ float bits_to_normal(uint32_t bits) {
  uint32_t fb = (bits >> 9) | 0x3F800000u;
  float f = __uint_as_float(fb) - 1.0f;
  const float lo = -0.99999994f;
  float u = fmaf(f, 1.0f - lo, lo);
  u = fmaxf(lo, u);
  return 1.41421356f * erfinv_xla(u);
}

// bf16 RNE helpers + hi/lo split
__device__ __forceinline__ uint32_t f2bf(float x) {
  uint32_t b = __float_as_uint(x);
  return (b + 0x7FFFu + ((b >> 16) & 1u)) >> 16;
}
__device__ __forceinline__ float bf2f_s(short h) {
  return __uint_as_float(((uint32_t)(uint16_t)h) << 16);
}
__device__ __forceinline__ void split_bf(float x, uint32_t& h, uint32_t& l) {
  h = f2bf(x);
  float hf = __uint_as_float(h << 16);
  l = f2bf(x - hf);
}

// branchless sorted-descending top-5 insert
__device__ __forceinline__ void ins5(float (&t)[5], float v) {
  float a = v;
#pragma unroll
  for (int q = 0; q < 5; ++q) {
    float hi = fmaxf(t[q], a);
    a = fminf(t[q], a);
    t[q] = hi;
  }
}

// ---------------------------------------------------------------------------
// MFMA worker. Block = one combo row-pair (rp, rp+512). 2 sample-passes of 64.
// C = [X | X@P]; X-cols' top-k taken from A-frag registers, Y-cols via MFMA
// in 32-col chunks with split-bf16 (3-pass) fp32-accurate matmul.
// ---------------------------------------------------------------------------
template <int K, int KP, int M>
__device__ void process_combo(const float* __restrict__ Pp,
                              const float* __restrict__ yp,
                              const float* __restrict__ yt,
                              float* __restrict__ accum,
                              int ofs, uint32_t key0, uint32_t key1,
                              int rp, char* sm) {
  constexpr int KSTEPS = KP / 32;
  constexpr int NCH = (K + 31) / 32;
  constexpr int PH = K / 2;            // k-pairs per sample
  constexpr int ITERS = PH / 4;        // genX iters (64*PH/256)
  constexpr int XSTR = KP + 8;         // bf16 elems per sample row (+16B pad)
  constexpr int BSTRU = KP / 2 + 4;    // uints per B col (+16B pad)
  constexpr int S_B = 32 * BSTRU * 4;  // bytes per B section
  constexpr int REGION = 4 * S_B;      // == 2*64*XSTR*2 (X one-row hi+lo)
  constexpr int XLO_U = REGION / 8;    // uint index of Xlo section
  constexpr uint32_t HALF = 65536u * (uint32_t)K;

  const int tid = threadIdx.x;
  const int wave = tid >> 6;
  const int lane = tid & 63;
  const int quad = lane >> 4;
  const int l15 = lane & 15;
  const int row = wave >> 1;           // data-row of this wave (0/1)
  const int msub = (wave & 1) * 32;    // sample offset of this wave

  const int b0 = 4 * rp + ofs;
  const int b1 = 4 * (rp + 512) + ofs;

  uint32_t* Xu = (uint32_t*)sm;        // X (one row at a time) / B region
  float* Ypool = (float*)(sm + REGION);
  float* Xpool = (float*)(sm + REGION + 20480);
  float* hmbuf = (float*)(sm + REGION + 20480 + 2560);
  float* maxhm = (float*)(sm + REGION + 20480 + 2560 + 512);

  if (tid < 2) maxhm[tid] = 0.0f;

  for (int pass = 0; pass < 2; ++pass) {
    // ---- Phase A: generate X. Write row0 to LDS, carry row1 in registers.
    uint32_t r1h[ITERS], r1l[ITERS];
#pragma unroll
    for (int it = 0; it < ITERS; ++it) {
      int q = it * 256 + tid;
      int s_loc = q / PH;
      int k = 2 * (q - s_loc * PH);
      uint32_t ctr = (uint32_t)((rp * 128 + pass * 64 + s_loc) * K + k);
      uint32_t o0a, o1a, o0b, o1b;
      tf2x32(key0, key1, ctr, ctr + HALF, o0a, o1a);
      tf2x32(key0, key1, ctr + 1u, ctr + 1u + HALF, o0b, o1b);
      float x0a = bits_to_normal(o0a), x0b = bits_to_normal(o0b);
      float x1a = bits_to_normal(o1a), x1b = bits_to_normal(o1b);
      uint32_t h0, l0, h1, l1;
      split_bf(x0a, h0, l0); split_bf(x0b, h1, l1);
      uint32_t idx = (uint32_t)(s_loc * XSTR + k) >> 1;
      Xu[idx] = h0 | (h1 << 16);
      Xu[XLO_U + idx] = l0 | (l1 << 16);
      split_bf(x1a, h0, l0); split_bf(x1b, h1, l1);
      r1h[it] = h0 | (h1 << 16);
      r1l[it] = l0 | (l1 << 16);
    }
    if constexpr (KP > K) {   // zero-pad k in [K,KP)
      for (int p = tid; p < 64 * (KP - K) / 2; p += 256) {
        int s = p / ((KP - K) / 2);
        int r = p - s * ((KP - K) / 2);
        uint32_t idx = (uint32_t)(s * XSTR + K) / 2 + r;
        Xu[idx] = 0; Xu[XLO_U + idx] = 0;
      }
    }
    __syncthreads();   // s1: row0 X visible

    bf16x8 ahi[2][KSTEPS], alo[2][KSTEPS];
    float t5x[2][5];

    // ---- A-frag load + X-col top-5 (waves of row0 first)
    auto load_a_and_t5x = [&]() {
#pragma unroll
      for (int f = 0; f < 2; ++f)
#pragma unroll
        for (int ks = 0; ks < KSTEPS; ++ks) {
          int off = (msub + f * 16 + l15) * XSTR * 2 + (ks * 32 + quad * 8) * 2;
          ahi[f][ks] = *(const bf16x8*)(sm + off);
          alo[f][ks] = *(const bf16x8*)(sm + REGION / 2 + off);
        }
#pragma unroll
      for (int f = 0; f < 2; ++f) {
#pragma unroll
        for (int q = 0; q < 5; ++q) t5x[f][q] = 0.0f;
#pragma unroll
        for (int ks = 0; ks < KSTEPS; ++ks)
#pragma unroll
          for (int j = 0; j < 8; ++j) {
            float v = bf2f_s(ahi[f][ks][j]) + bf2f_s(alo[f][ks][j]);
            ins5(t5x[f], fabsf(v));
          }
      }
      // quad-butterfly merge -> full X top5 per sample
#pragma unroll
      for (int f = 0; f < 2; ++f) {
#pragma unroll
        for (int msk = 16; msk <= 32; msk <<= 1) {
          float o[5];
#pragma unroll
          for (int q = 0; q < 5; ++q) o[q] = __shfl_xor(t5x[f][q], msk);
#pragma unroll
          for (int q = 0; q < 5; ++q) ins5(t5x[f], o[q]);
        }
      }
      if (lane < 16) {
#pragma unroll
        for (int f = 0; f < 2; ++f) {
          int slot = row * 64 + msub + f * 16 + l15;
#pragma unroll
          for (int q = 0; q < 5; ++q) Xpool[slot * 5 + q] = t5x[f][q];
        }
      }
    };

    if (wave < 2) load_a_and_t5x();
    __syncthreads();   // s2: row0 consumers done

    // write row1 X from carried registers
#pragma unroll
    for (int it = 0; it < ITERS; ++it) {
      int q = it * 256 + tid;
      int s_loc = q / PH;
      int k = 2 * (q - s_loc * PH);
      uint32_t idx = (uint32_t)(s_loc * XSTR + k) >> 1;
      Xu[idx] = r1h[it];
      Xu[XLO_U + idx] = r1l[it];
    }
    if constexpr (KP > K) {
      for (int p = tid; p < 64 * (KP - K) / 2; p += 256) {
        int s = p / ((KP - K) / 2);
        int r = p - s * ((KP - K) / 2);
        uint32_t idx = (uint32_t)(s * XSTR + K) / 2 + r;
        Xu[idx] = 0; Xu[XLO_U + idx] = 0;
      }
    }
    __syncthreads();   // s3: row1 X visible

    if (wave >= 2) load_a_and_t5x();
    __syncthreads();   // s4: X region free -> B staging may begin

    // ---- Y chunks: stage B (P cols, transposed, split-bf16), MFMA, top-5
    float t5y[2][4][5];
#pragma unroll
    for (int f = 0; f < 2; ++f)
#pragma unroll
      for (int r = 0; r < 4; ++r)
#pragma unroll
        for (int q = 0; q < 5; ++q) t5y[f][r][q] = 0.0f;

    for (int c = 0; c < NCH; ++c) {
      const int jb = c * 32;
      // stage: Bt[row][part][j][kk2], zero-padded
      for (int it2 = 0; it2 < KP / 8; ++it2) {
        int q = it2 * 256 + tid;
        int j = q & 31;
        int t = q >> 5;
        int rowq = t / (KP / 2);
        int kk2 = t - rowq * (KP / 2);
        int col = jb + j;
        int kk = 2 * kk2;
        const float* Pr = Pp + (size_t)(rowq ? b1 : b0) * 16384;
        float v0 = 0.0f, v1 = 0.0f;
        if (col < K) {
          if (kk < K)     v0 = Pr[kk * 128 + col];
          if (kk + 1 < K) v1 = Pr[(kk + 1) * 128 + col];
        }
        uint32_t h0, l0, h1, l1;
        split_bf(v0, h0, l0); split_bf(v1, h1, l1);
        uint32_t uidx = (uint32_t)(j * BSTRU + kk2);
        ((uint32_t*)(sm + (2 * rowq) * S_B))[uidx] = h0 | (h1 << 16);
        ((uint32_t*)(sm + (2 * rowq + 1) * S_B))[uidx] = l0 | (l1 << 16);
      }
      __syncthreads();

      f32x4 acc[2][2];
#pragma unroll
      for (int f = 0; f < 2; ++f)
#pragma unroll
        for (int nf = 0; nf < 2; ++nf) acc[f][nf] = (f32x4){0.f, 0.f, 0.f, 0.f};

#pragma unroll
      for (int ks = 0; ks < KSTEPS; ++ks) {
        bf16x8 bh[2], bl[2];
#pragma unroll
        for (int nf = 0; nf < 2; ++nf) {
          int uidx = (nf * 16 + l15) * BSTRU + ks * 16 + quad * 4;
          bh[nf] = *(const bf16x8*)(sm + (2 * row) * S_B + uidx * 4);
          bl[nf] = *(const bf16x8*)(sm + (2 * row + 1) * S_B + uidx * 4);
        }
#pragma unroll
        for (int f = 0; f < 2; ++f)
#pragma unroll
          for (int nf = 0; nf < 2; ++nf) {
            acc[f][nf] = __builtin_amdgcn_mfma_f32_16x16x32_bf16(ahi[f][ks], bh[nf], acc[f][nf], 0, 0, 0);
            acc[f][nf] = __builtin_amdgcn_mfma_f32_16x16x32_bf16(ahi[f][ks], bl[nf], acc[f][nf], 0, 0, 0);
            acc[f][nf] = __builtin_amdgcn_mfma_f32_16x16x32_bf16(alo[f][ks], bh[nf], acc[f][nf], 0, 0, 0);
          }
      }
#pragma unroll
      for (int f = 0; f < 2; ++f)
#pragma unroll
        for (int nf = 0; nf < 2; ++nf)
#pragma unroll
          for (int r = 0; r < 4; ++r)
            ins5(t5y[f][r], fabsf(acc[f][nf][r]));
      __syncthreads();   // B region re-stageable
    }

    // xor-1 lane merge (pairs of col-partials), write Ypool
#pragma unroll
    for (int f = 0; f < 2; ++f)
#pragma unroll
      for (int r = 0; r < 4; ++r) {
        float o[5];
#pragma unroll
        for (int q = 0; q < 5; ++q) o[q] = __shfl_xor(t5y[f][r][q], 1);
#pragma unroll
        for (int q = 0; q < 5; ++q) ins5(t5y[f][r], o[q]);
      }
    if (!(lane & 1)) {
      int p = l15 >> 1;
#pragma unroll
      for (int f = 0; f < 2; ++f)
#pragma unroll
        for (int r = 0; r < 4; ++r) {
          int slot = row * 64 + msub + f * 16 + quad * 4 + r;
#pragma unroll
          for (int q = 0; q < 5; ++q)
            Ypool[(slot * 8 + p) * 5 + q] = t5y[f][r][q];
        }
    }
    __syncthreads();

    // merge per sample: X top5 (already full) + 8 Y partials
    if (tid < 128) {
      float t5[5];
#pragma unroll
      for (int q = 0; q < 5; ++q) t5[q] = Xpool[tid * 5 + q];
      for (int q = 0; q < 40; ++q) ins5(t5, Ypool[tid * 40 + q]);
      hmbuf[tid] = t5[0] / (t5[M] + 1e-9f);
    }
    __syncthreads();
    if (tid < 2) {
      float mx = maxhm[tid];
      for (int s = 0; s < 64; ++s) mx = fmaxf(mx, hmbuf[tid * 64 + s]);
      maxhm[tid] = mx;
    }
    __syncthreads();
  }

  if (tid == 0) {
    float pen = fmaxf(maxhm[0] - yp[b0], 0.0f) + fmaxf(maxhm[1] - yp[b1], 0.0f);
    atomicAdd(&accum[0], pen);
    float d0 = log2f(fmaxf(yt[b0], 1e-9f)) - log2f(fmaxf(yp[b0], 1e-9f));
    float d1 = log2f(fmaxf(yt[b1], 1e-9f)) - log2f(fmaxf(yp[b1], 1e-9f));
    atomicAdd(&accum[1], fmaf(d0, d0, d1 * d1));
  }
}

struct ComboArgs {
  int ofs[4];
  uint32_t k0[4];
  uint32_t k1[4];
};

#define SM_BYTES (34816 + 20480 + 2560 + 512 + 16)

__global__ __launch_bounds__(256, 2)
void viol_kernel(const float* __restrict__ Pp, const float* __restrict__ yp,
                 const float* __restrict__ yt, float* __restrict__ accum,
                 ComboArgs ca) {
  __shared__ __align__(16) char sm[SM_BYTES];
  int i = blockIdx.x >> 9;
  int rp = blockIdx.x & 511;
  switch (i) {
    case 0: process_combo< 80,  96, 2>(Pp, yp, yt, accum, ca.ofs[0], ca.k0[0], ca.k1[0], rp, sm); break;
    case 1: process_combo< 96,  96, 3>(Pp, yp, yt, accum, ca.ofs[1], ca.k0[1], ca.k1[1], rp, sm); break;
    case 2: process_combo<112, 128, 4>(Pp, yp, yt, accum, ca.ofs[2], ca.k0[2], ca.k1[2], rp, sm); break;
    default: process_combo<128, 128, 3>(Pp, yp, yt, accum, ca.ofs[3], ca.k0[3], ca.k1[3], rp, sm); break;
  }
}

__global__ void finalize_kernel(const float* __restrict__ accum, float* __restrict__ out) {
  if (threadIdx.x == 0 && blockIdx.x == 0) {
    float viol = accum[0] / 4096.0f;
    float lm = accum[1] / 4096.0f;
    out[0] = fmaf(0.5f, viol, lm);
    out[1] = lm;
    out[2] = viol;
  }
}

extern "C" void kernel_launch(void* const* d_in, const int* in_sizes, int n_in,
                              void* d_out, int out_size, void* d_ws, size_t ws_size,
                              hipStream_t stream) {
  const float* y_pred   = (const float*)d_in[0];
  const float* y_true   = (const float*)d_in[1];
  const float* P_padded = (const float*)d_in[2];
  float* accum = (float*)d_ws;
  float* out = (float*)d_out;

  hipMemsetAsync(accum, 0, 2 * sizeof(float), stream);

  // combos sorted as np.unique: (160,80,2)<-b%4==3, (192,96,3)<-1, (224,112,4)<-2, (256,128,3)<-0
  ComboArgs ca;
  const int ofs[4] = {3, 1, 2, 0};
  for (int i = 0; i < 4; ++i) {
    ca.ofs[i] = ofs[i];
    uint32_t o0, o1;
    tf2x32(0u, 42u, 0u, (uint32_t)i, o0, o1);  // fold_in(key(42), i)
    ca.k0[i] = o0;
    ca.k1[i] = o1;
  }

  viol_kernel<<<2048, 256, 0, stream>>>(P_padded, y_pred, y_true, accum, ca);
  finalize_kernel<<<1, 64, 0, stream>>>(accum, out);
}

// Round 3
// 706.904 us; speedup vs baseline: 1.8181x; 1.0883x over previous
//
#include <hip/hip_runtime.h>
#include <stdint.h>

typedef short bf16x8 __attribute__((ext_vector_type(8)));
typedef float f32x4 __attribute__((ext_vector_type(4)));

// ---------------------------------------------------------------------------
// Threefry-2x32 (JAX/Random123 schedule)
// ---------------------------------------------------------------------------
__host__ __device__ inline uint32_t rotl32(uint32_t v, int d) {
  return (v << d) | (v >> (32 - d));
}

__host__ __device__ inline void tf2x32(uint32_t k0, uint32_t k1,
                                       uint32_t x0, uint32_t x1,
                                       uint32_t& o0, uint32_t& o1) {
  uint32_t ks0 = k0, ks1 = k1, ks2 = k0 ^ k1 ^ 0x1BD11BDAu;
  x0 += ks0; x1 += ks1;
#define TF_R(r) { x0 += x1; x1 = rotl32(x1, (r)); x1 ^= x0; }
  TF_R(13) TF_R(15) TF_R(26) TF_R(6)
  x0 += ks1; x1 += ks2 + 1u;
  TF_R(17) TF_R(29) TF_R(16) TF_R(24)
  x0 += ks2; x1 += ks0 + 2u;
  TF_R(13) TF_R(15) TF_R(26) TF_R(6)
  x0 += ks0; x1 += ks1 + 3u;
  TF_R(17) TF_R(29) TF_R(16) TF_R(24)
  x0 += ks1; x1 += ks2 + 4u;
  TF_R(13) TF_R(15) TF_R(26) TF_R(6)
  x0 += ks2; x1 += ks0 + 5u;
#undef TF_R
  o0 = x0; o1 = x1;
}

// XLA's fp32 erf_inv (Giles polynomial); log1p replaced by fast v_log path
__device__ __forceinline__ float erfinv_xla(float x) {
  float w = -__logf(fmaf(-x, x, 1.0f));
  float p;
  if (w < 5.0f) {
    w = w - 2.5f;
    p = 2.81022636e-08f;
    p = fmaf(p, w, 3.43273939e-07f);
    p = fmaf(p, w, -3.5233877e-06f);
    p = fmaf(p, w, -4.39150654e-06f);
    p = fmaf(p, w, 0.00021858087f);
    p = fmaf(p, w, -0.00125372503f);
    p = fmaf(p, w, -0.00417768164f);
    p = fmaf(p, w, 0.246640727f);
    p = fmaf(p, w, 1.50140941f);
  } else {
    w = sqrtf(w) - 3.0f;
    p = -0.000200214257f;
    p = fmaf(p, w, 0.000100950558f);
    p = fmaf(p, w, 0.00134934322f);
    p = fmaf(p, w, -0.00367342844f);
    p = fmaf(p, w, 0.00573950773f);
    p = fmaf(p, w, -0.0076224613f);
    p = fmaf(p, w, 0.00943887047f);
    p = fmaf(p, w, 1.00167406f);
    p = fmaf(p, w, 2.83297682f);
  }
  return p * x;
}

__device__ __forceinline__ float bits_to_normal(uint32_t bits) {
  uint32_t fb = (bits >> 9) | 0x3F800000u;
  float f = __uint_as_float(fb) - 1.0f;
  const float lo = -0.99999994f;
  float u = fmaf(f, 1.0f - lo, lo);
  u = fmaxf(lo, u);
  return 1.41421356f * erfinv_xla(u);
}

// bf16 RNE helpers + hi/lo split
__device__ __forceinline__ uint32_t f2bf(float x) {
  uint32_t b = __float_as_uint(x);
  return (b + 0x7FFFu + ((b >> 16) & 1u)) >> 16;
}
__device__ __forceinline__ float bf2f_s(short h) {
  return __uint_as_float(((uint32_t)(uint16_t)h) << 16);
}
__device__ __forceinline__ void split_bf(float x, uint32_t& h, uint32_t& l) {
  h = f2bf(x);
  float hf = __uint_as_float(h << 16);
  l = f2bf(x - hf);
}

// branchless sorted-descending top-T insert
template <int T>
__device__ __forceinline__ void insT(float (&t)[T], float v) {
  float a = v;
#pragma unroll
  for (int q = 0; q < T; ++q) {
    float hi = fmaxf(t[q], a);
    a = fminf(t[q], a);
    t[q] = hi;
  }
}

// ---------------------------------------------------------------------------
// MFMA worker. Block = one combo row-pair (rp, rp+512). 2 sample-passes of 64.
// C = [X | X@P]; X-col top-T from A-frag registers, Y via split-bf16 3-pass
// MFMA in 32-col chunks; Y top-T merged fully in-wave (no LDS pool).
// T = m+1 (tracker depth).
// ---------------------------------------------------------------------------
template <int K, int KP, int T>
__device__ void process_combo(const float* __restrict__ Pp,
                              const float* __restrict__ yp,
                              const float* __restrict__ yt,
                              float* __restrict__ accum,
                              int ofs, uint32_t key0, uint32_t key1,
                              int rp, char* sm) {
  constexpr int KSTEPS = KP / 32;
  constexpr int NCH = (K + 31) / 32;
  constexpr int PH = K / 2;            // k-pairs per sample
  constexpr int ITERS = PH / 4;        // genX iters (64*PH/256)
  constexpr int XSTR = KP + 8;         // bf16 elems per sample row (+16B pad)
  constexpr int BSTRU = KP / 2 + 4;    // uints per B col (+16B pad)
  constexpr int S_B = 32 * BSTRU * 4;  // bytes per B section
  constexpr int REGION = 4 * S_B;      // == 2*64*XSTR*2 (X one-row hi+lo)
  constexpr int XLO_U = REGION / 8;    // uint index of Xlo section
  constexpr uint32_t HALF = 65536u * (uint32_t)K;

  const int tid = threadIdx.x;
  const int wave = tid >> 6;
  const int lane = tid & 63;
  const int quad = lane >> 4;
  const int l15 = lane & 15;
  const int row = wave >> 1;           // data-row of this wave (0/1)
  const int msub = (wave & 1) * 32;    // sample offset of this wave

  const int b0 = 4 * rp + ofs;
  const int b1 = 4 * (rp + 512) + ofs;

  uint32_t* Xu = (uint32_t*)sm;        // X (one row at a time) / B region
  float* Xpool = (float*)(sm + REGION);    // 128 * T floats
  float* wvmax = Xpool + 128 * T;          // 4 floats
  float* maxhm = wvmax + 4;                // 2 floats

  if (tid < 2) maxhm[tid] = 0.0f;

  for (int pass = 0; pass < 2; ++pass) {
    // ---- Phase A: generate X. Write row0 to LDS, carry row1 in registers.
    uint32_t r1h[ITERS], r1l[ITERS];
#pragma unroll
    for (int it = 0; it < ITERS; ++it) {
      int q = it * 256 + tid;
      int s_loc = q / PH;
      int k = 2 * (q - s_loc * PH);
      uint32_t ctr = (uint32_t)((rp * 128 + pass * 64 + s_loc) * K + k);
      uint32_t o0a, o1a, o0b, o1b;
      tf2x32(key0, key1, ctr, ctr + HALF, o0a, o1a);
      tf2x32(key0, key1, ctr + 1u, ctr + 1u + HALF, o0b, o1b);
      float x0a = bits_to_normal(o0a), x0b = bits_to_normal(o0b);
      float x1a = bits_to_normal(o1a), x1b = bits_to_normal(o1b);
      uint32_t h0, l0, h1, l1;
      split_bf(x0a, h0, l0); split_bf(x0b, h1, l1);
      uint32_t idx = (uint32_t)(s_loc * XSTR + k) >> 1;
      Xu[idx] = h0 | (h1 << 16);
      Xu[XLO_U + idx] = l0 | (l1 << 16);
      split_bf(x1a, h0, l0); split_bf(x1b, h1, l1);
      r1h[it] = h0 | (h1 << 16);
      r1l[it] = l0 | (l1 << 16);
    }
    if constexpr (KP > K) {   // zero-pad k in [K,KP)
      for (int p = tid; p < 64 * (KP - K) / 2; p += 256) {
        int s = p / ((KP - K) / 2);
        int r = p - s * ((KP - K) / 2);
        uint32_t idx = (uint32_t)(s * XSTR + K) / 2 + r;
        Xu[idx] = 0; Xu[XLO_U + idx] = 0;
      }
    }
    __syncthreads();   // s1: row0 X visible

    bf16x8 ahi[2][KSTEPS], alo[2][KSTEPS];

    // ---- A-frag load + X-col top-T -> Xpool (waves of row0 first)
    auto load_a_and_t5x = [&]() {
#pragma unroll
      for (int f = 0; f < 2; ++f)
#pragma unroll
        for (int ks = 0; ks < KSTEPS; ++ks) {
          int off = (msub + f * 16 + l15) * XSTR * 2 + (ks * 32 + quad * 8) * 2;
          ahi[f][ks] = *(const bf16x8*)(sm + off);
          alo[f][ks] = *(const bf16x8*)(sm + REGION / 2 + off);
        }
      float t5x[2][T];
#pragma unroll
      for (int f = 0; f < 2; ++f) {
#pragma unroll
        for (int q = 0; q < T; ++q) t5x[f][q] = 0.0f;
#pragma unroll
        for (int ks = 0; ks < KSTEPS; ++ks)
#pragma unroll
          for (int j = 0; j < 8; ++j) {
            float v = bf2f_s(ahi[f][ks][j]) + bf2f_s(alo[f][ks][j]);
            insT(t5x[f], fabsf(v));
          }
      }
      // quad-butterfly merge -> full X top-T per sample
#pragma unroll
      for (int f = 0; f < 2; ++f) {
#pragma unroll
        for (int msk = 16; msk <= 32; msk <<= 1) {
          float o[T];
#pragma unroll
          for (int q = 0; q < T; ++q) o[q] = __shfl_xor(t5x[f][q], msk);
#pragma unroll
          for (int q = 0; q < T; ++q) insT(t5x[f], o[q]);
        }
      }
      if (lane < 16) {
#pragma unroll
        for (int f = 0; f < 2; ++f) {
          int slot = row * 64 + msub + f * 16 + l15;
#pragma unroll
          for (int q = 0; q < T; ++q) Xpool[slot * T + q] = t5x[f][q];
        }
      }
    };

    if (wave < 2) load_a_and_t5x();
    __syncthreads();   // s2: row0 consumers done

    // write row1 X from carried registers
#pragma unroll
    for (int it = 0; it < ITERS; ++it) {
      int q = it * 256 + tid;
      int s_loc = q / PH;
      int k = 2 * (q - s_loc * PH);
      uint32_t idx = (uint32_t)(s_loc * XSTR + k) >> 1;
      Xu[idx] = r1h[it];
      Xu[XLO_U + idx] = r1l[it];
    }
    if constexpr (KP > K) {
      for (int p = tid; p < 64 * (KP - K) / 2; p += 256) {
        int s = p / ((KP - K) / 2);
        int r = p - s * ((KP - K) / 2);
        uint32_t idx = (uint32_t)(s * XSTR + K) / 2 + r;
        Xu[idx] = 0; Xu[XLO_U + idx] = 0;
      }
    }
    __syncthreads();   // s3: row1 X visible

    if (wave >= 2) load_a_and_t5x();
    __syncthreads();   // s4: X region free -> B staging may begin

    // ---- Y chunks: stage B (P cols, transposed, split-bf16), MFMA, top-T
    float t5y[2][4][T];
#pragma unroll
    for (int f = 0; f < 2; ++f)
#pragma unroll
      for (int r = 0; r < 4; ++r)
#pragma unroll
        for (int q = 0; q < T; ++q) t5y[f][r][q] = 0.0f;

    for (int c = 0; c < NCH; ++c) {
      const int jb = c * 32;
      // stage: Bt[row][part][j][kk2], zero-padded
      for (int it2 = 0; it2 < KP / 8; ++it2) {
        int q = it2 * 256 + tid;
        int j = q & 31;
        int t = q >> 5;
        int rowq = t / (KP / 2);
        int kk2 = t - rowq * (KP / 2);
        int col = jb + j;
        int kk = 2 * kk2;
        const float* Pr = Pp + (size_t)(rowq ? b1 : b0) * 16384;
        float v0 = 0.0f, v1 = 0.0f;
        if (col < K) {
          if (kk < K)     v0 = Pr[kk * 128 + col];
          if (kk + 1 < K) v1 = Pr[(kk + 1) * 128 + col];
        }
        uint32_t h0, l0, h1, l1;
        split_bf(v0, h0, l0); split_bf(v1, h1, l1);
        uint32_t uidx = (uint32_t)(j * BSTRU + kk2);
        ((uint32_t*)(sm + (2 * rowq) * S_B))[uidx] = h0 | (h1 << 16);
        ((uint32_t*)(sm + (2 * rowq + 1) * S_B))[uidx] = l0 | (l1 << 16);
      }
      __syncthreads();

      f32x4 acc[2][2];
#pragma unroll
      for (int f = 0; f < 2; ++f)
#pragma unroll
        for (int nf = 0; nf < 2; ++nf) acc[f][nf] = (f32x4){0.f, 0.f, 0.f, 0.f};

#pragma unroll
      for (int ks = 0; ks < KSTEPS; ++ks) {
        bf16x8 bh[2], bl[2];
#pragma unroll
        for (int nf = 0; nf < 2; ++nf) {
          int uidx = (nf * 16 + l15) * BSTRU + ks * 16 + quad * 4;
          bh[nf] = *(const bf16x8*)(sm + (2 * row) * S_B + uidx * 4);
          bl[nf] = *(const bf16x8*)(sm + (2 * row + 1) * S_B + uidx * 4);
        }
#pragma unroll
        for (int f = 0; f < 2; ++f)
#pragma unroll
          for (int nf = 0; nf < 2; ++nf) {
            acc[f][nf] = __builtin_amdgcn_mfma_f32_16x16x32_bf16(ahi[f][ks], bh[nf], acc[f][nf], 0, 0, 0);
            acc[f][nf] = __builtin_amdgcn_mfma_f32_16x16x32_bf16(ahi[f][ks], bl[nf], acc[f][nf], 0, 0, 0);
            acc[f][nf] = __builtin_amdgcn_mfma_f32_16x16x32_bf16(alo[f][ks], bh[nf], acc[f][nf], 0, 0, 0);
          }
      }
#pragma unroll
      for (int f = 0; f < 2; ++f)
#pragma unroll
        for (int nf = 0; nf < 2; ++nf)
#pragma unroll
          for (int r = 0; r < 4; ++r)
            insT(t5y[f][r], fabsf(acc[f][nf][r]));
      __syncthreads();   // B region re-stageable
    }

    // ---- in-wave merge: full l15 butterfly + Xpool merge + hm + wave max
    float wmax = 0.0f;
#pragma unroll
    for (int f = 0; f < 2; ++f)
#pragma unroll
      for (int r = 0; r < 4; ++r) {
#pragma unroll
        for (int msk = 1; msk <= 8; msk <<= 1) {
          float o[T];
#pragma unroll
          for (int q = 0; q < T; ++q) o[q] = __shfl_xor(t5y[f][r][q], msk);
#pragma unroll
          for (int q = 0; q < T; ++q) insT(t5y[f][r], o[q]);
        }
        int slot = row * 64 + msub + f * 16 + quad * 4 + r;
        const float* xp = Xpool + slot * T;
#pragma unroll
        for (int q = 0; q < T; ++q) insT(t5y[f][r], xp[q]);
        float hm = t5y[f][r][0] / (t5y[f][r][T - 1] + 1e-9f);
        wmax = fmaxf(wmax, hm);
      }
    wmax = fmaxf(wmax, __shfl_xor(wmax, 16));
    wmax = fmaxf(wmax, __shfl_xor(wmax, 32));
    if (lane == 0) wvmax[wave] = wmax;
    __syncthreads();
    if (tid < 2)
      maxhm[tid] = fmaxf(maxhm[tid], fmaxf(wvmax[2 * tid], wvmax[2 * tid + 1]));
  }

  if (tid == 0) {
    float pen = fmaxf(maxhm[0] - yp[b0], 0.0f) + fmaxf(maxhm[1] - yp[b1], 0.0f);
    atomicAdd(&accum[0], pen);
    float d0 = log2f(fmaxf(yt[b0], 1e-9f)) - log2f(fmaxf(yp[b0], 1e-9f));
    float d1 = log2f(fmaxf(yt[b1], 1e-9f)) - log2f(fmaxf(yp[b1], 1e-9f));
    atomicAdd(&accum[1], fmaf(d0, d0, d1 * d1));
  }
}

struct ComboArgs {
  int ofs[4];
  uint32_t k0[4];
  uint32_t k1[4];
};

// max REGION (KP=128) + Xpool(128*5*4) + wvmax(16) + maxhm(8)
#define SM_BYTES (34816 + 2560 + 16 + 8 + 8)

__global__ __launch_bounds__(256, 4)
void viol_kernel(const float* __restrict__ Pp, const float* __restrict__ yp,
                 const float* __restrict__ yt, float* __restrict__ accum,
                 ComboArgs ca) {
  __shared__ __align__(16) char sm[SM_BYTES];
  int i = blockIdx.x >> 9;
  int rp = blockIdx.x & 511;
  switch (i) {
    case 0: process_combo< 80,  96, 3>(Pp, yp, yt, accum, ca.ofs[0], ca.k0[0], ca.k1[0], rp, sm); break;
    case 1: process_combo< 96,  96, 4>(Pp, yp, yt, accum, ca.ofs[1], ca.k0[1], ca.k1[1], rp, sm); break;
    case 2: process_combo<112, 128, 5>(Pp, yp, yt, accum, ca.ofs[2], ca.k0[2], ca.k1[2], rp, sm); break;
    default: process_combo<128, 128, 4>(Pp, yp, yt, accum, ca.ofs[3], ca.k0[3], ca.k1[3], rp, sm); break;
  }
}

__global__ void finalize_kernel(const float* __restrict__ accum, float* __restrict__ out) {
  if (threadIdx.x == 0 && blockIdx.x == 0) {
    float viol = accum[0] / 4096.0f;
    float lm = accum[1] / 4096.0f;
    out[0] = fmaf(0.5f, viol, lm);
    out[1] = lm;
    out[2] = viol;
  }
}

extern "C" void kernel_launch(void* const* d_in, const int* in_sizes, int n_in,
                              void* d_out, int out_size, void* d_ws, size_t ws_size,
                              hipStream_t stream) {
  const float* y_pred   = (const float*)d_in[0];
  const float* y_true   = (const float*)d_in[1];
  const float* P_padded = (const float*)d_in[2];
  float* accum = (float*)d_ws;
  float* out = (float*)d_out;

  hipMemsetAsync(accum, 0, 2 * sizeof(float), stream);

  // combos sorted as np.unique: (160,80,2)<-b%4==3, (192,96,3)<-1, (224,112,4)<-2, (256,128,3)<-0
  ComboArgs ca;
  const int ofs[4] = {3, 1, 2, 0};
  for (int i = 0; i < 4; ++i) {
    ca.ofs[i] = ofs[i];
    uint32_t o0, o1;
    tf2x32(0u, 42u, 0u, (uint32_t)i, o0, o1);  // fold_in(key(42), i)
    ca.k0[i] = o0;
    ca.k1[i] = o1;
  }

  viol_kernel<<<2048, 256, 0, stream>>>(P_padded, y_pred, y_true, accum, ca);
  finalize_kernel<<<1, 64, 0, stream>>>(accum, out);
}

// Round 4
// 613.955 us; speedup vs baseline: 2.0934x; 1.1514x over previous
//
#include <hip/hip_runtime.h>
#include <stdint.h>

typedef short bf16x8 __attribute__((ext_vector_type(8)));
typedef float f32x4 __attribute__((ext_vector_type(4)));

// ---------------------------------------------------------------------------
// Threefry-2x32 (JAX/Random123 schedule)
// ---------------------------------------------------------------------------
__host__ __device__ inline uint32_t rotl32(uint32_t v, int d) {
  return (v << d) | (v >> (32 - d));
}

__host__ __device__ inline void tf2x32(uint32_t k0, uint32_t k1,
                                       uint32_t x0, uint32_t x1,
                                       uint32_t& o0, uint32_t& o1) {
  uint32_t ks0 = k0, ks1 = k1, ks2 = k0 ^ k1 ^ 0x1BD11BDAu;
  x0 += ks0; x1 += ks1;
#define TF_R(r) { x0 += x1; x1 = rotl32(x1, (r)); x1 ^= x0; }
  TF_R(13) TF_R(15) TF_R(26) TF_R(6)
  x0 += ks1; x1 += ks2 + 1u;
  TF_R(17) TF_R(29) TF_R(16) TF_R(24)
  x0 += ks2; x1 += ks0 + 2u;
  TF_R(13) TF_R(15) TF_R(26) TF_R(6)
  x0 += ks0; x1 += ks1 + 3u;
  TF_R(17) TF_R(29) TF_R(16) TF_R(24)
  x0 += ks1; x1 += ks2 + 4u;
  TF_R(13) TF_R(15) TF_R(26) TF_R(6)
  x0 += ks2; x1 += ks0 + 5u;
#undef TF_R
  o0 = x0; o1 = x1;
}

// XLA's fp32 erf_inv (Giles polynomial); log1p via fast v_log path
__device__ __forceinline__ float erfinv_xla(float x) {
  float w = -__logf(fmaf(-x, x, 1.0f));
  float p;
  if (w < 5.0f) {
    w = w - 2.5f;
    p = 2.81022636e-08f;
    p = fmaf(p, w, 3.43273939e-07f);
    p = fmaf(p, w, -3.5233877e-06f);
    p = fmaf(p, w, -4.39150654e-06f);
    p = fmaf(p, w, 0.00021858087f);
    p = fmaf(p, w, -0.00125372503f);
    p = fmaf(p, w, -0.00417768164f);
    p = fmaf(p, w, 0.246640727f);
    p = fmaf(p, w, 1.50140941f);
  } else {
    w = sqrtf(w) - 3.0f;
    p = -0.000200214257f;
    p = fmaf(p, w, 0.000100950558f);
    p = fmaf(p, w, 0.00134934322f);
    p = fmaf(p, w, -0.00367342844f);
    p = fmaf(p, w, 0.00573950773f);
    p = fmaf(p, w, -0.0076224613f);
    p = fmaf(p, w, 0.00943887047f);
    p = fmaf(p, w, 1.00167406f);
    p = fmaf(p, w, 2.83297682f);
  }
  return p * x;
}

__device__ __forceinline__ float bits_to_normal(uint32_t bits) {
  uint32_t fb = (bits >> 9) | 0x3F800000u;
  float f = __uint_as_float(fb) - 1.0f;
  const float lo = -0.99999994f;
  float u = fmaf(f, 1.0f - lo, lo);
  u = fmaxf(lo, u);
  return 1.41421356f * erfinv_xla(u);
}

// bf16 RNE round
__device__ __forceinline__ uint32_t f2bf(float x) {
  uint32_t b = __float_as_uint(x);
  return (b + 0x7FFFu + ((b >> 16) & 1u)) >> 16;
}
__device__ __forceinline__ float bf2f_s(short h) {
  return __uint_as_float(((uint32_t)(uint16_t)h) << 16);
}

// branchless sorted-descending top-T insert
template <int T>
__device__ __forceinline__ void insT(float (&t)[T], float v) {
  float a = v;
#pragma unroll
  for (int q = 0; q < T; ++q) {
    float hi = fmaxf(t[q], a);
    a = fminf(t[q], a);
    t[q] = hi;
  }
}

// ---------------------------------------------------------------------------
// MFMA worker. Block = one combo row-pair (rp, rp+512). 2 sample-passes of 64.
// Pure-bf16 matmul (1 MFMA pass). Both rows' X resident in one LDS region;
// B staging reuses the region after A-frags are in registers. T = m+1.
// ---------------------------------------------------------------------------
template <int K, int KP, int T>
__device__ void process_combo(const float* __restrict__ Pp,
                              const float* __restrict__ yp,
                              const float* __restrict__ yt,
                              float* __restrict__ accum,
                              int ofs, uint32_t key0, uint32_t key1,
                              int rp, char* sm) {
  constexpr int KSTEPS = KP / 32;
  constexpr int NCH = (K + 31) / 32;
  constexpr int PH = K / 2;            // k-pairs per sample per row
  constexpr int ITERS = PH / 4;        // genX iters (64*PH/256)
  constexpr int XSTR = KP + 8;         // bf16 elems per sample row (+16B pad)
  constexpr int XSTRU = XSTR / 2;      // uints per sample row
  constexpr int XROW_U = 64 * XSTRU;   // uints per data-row section
  constexpr int BSTRU = KP / 2 + 4;    // uints per B col (+16B pad)
  constexpr int S_B = 32 * BSTRU * 4;  // bytes per B row-section
  constexpr int REGION = 2 * 64 * XSTR * 2;  // X both rows (>= 2*S_B)
  constexpr uint32_t HALF = 65536u * (uint32_t)K;

  const int tid = threadIdx.x;
  const int wave = tid >> 6;
  const int lane = tid & 63;
  const int quad = lane >> 4;
  const int l15 = lane & 15;
  const int row = wave >> 1;           // data-row of this wave (0/1)
  const int msub = (wave & 1) * 32;    // sample offset of this wave

  const int b0 = 4 * rp + ofs;
  const int b1 = 4 * (rp + 512) + ofs;

  uint32_t* Xu = (uint32_t*)sm;            // X both rows / B region
  float* Xpool = (float*)(sm + REGION);    // 128 * T floats
  float* wvmax = Xpool + 128 * T;          // 4 floats
  float* maxhm = wvmax + 4;                // 2 floats

  if (tid < 2) maxhm[tid] = 0.0f;

  for (int pass = 0; pass < 2; ++pass) {
    // ---- Phase A: generate X (both rows) straight to LDS as bf16
#pragma unroll
    for (int it = 0; it < ITERS; ++it) {
      int q = it * 256 + tid;
      int s_loc = q / PH;
      int k = 2 * (q - s_loc * PH);
      uint32_t ctr = (uint32_t)((rp * 128 + pass * 64 + s_loc) * K + k);
      uint32_t o0a, o1a, o0b, o1b;
      tf2x32(key0, key1, ctr, ctr + HALF, o0a, o1a);
      tf2x32(key0, key1, ctr + 1u, ctr + 1u + HALF, o0b, o1b);
      uint32_t idx = (uint32_t)(s_loc * XSTRU + (k >> 1));
      uint32_t h0 = f2bf(bits_to_normal(o0a));
      uint32_t h1 = f2bf(bits_to_normal(o0b));
      Xu[idx] = h0 | (h1 << 16);
      h0 = f2bf(bits_to_normal(o1a));
      h1 = f2bf(bits_to_normal(o1b));
      Xu[XROW_U + idx] = h0 | (h1 << 16);
    }
    if constexpr (KP > K) {   // zero-pad k in [K,KP) for both rows
      constexpr int PADU = (KP - K) / 2;
      for (int p = tid; p < 2 * 64 * PADU; p += 256) {
        int rs = p / PADU;
        int r = p - rs * PADU;
        Xu[rs * XSTRU + K / 2 + r] = 0;
      }
    }
    __syncthreads();   // s1: X visible

    // ---- A-frag load + X-col top-T -> Xpool
    bf16x8 ahi[2][KSTEPS];
#pragma unroll
    for (int f = 0; f < 2; ++f)
#pragma unroll
      for (int ks = 0; ks < KSTEPS; ++ks) {
        int off = ((row * 64 + msub + f * 16 + l15) * XSTR + ks * 32 + quad * 8) * 2;
        ahi[f][ks] = *(const bf16x8*)(sm + off);
      }
    {
      float t5x[2][T];
#pragma unroll
      for (int f = 0; f < 2; ++f) {
#pragma unroll
        for (int q = 0; q < T; ++q) t5x[f][q] = 0.0f;
#pragma unroll
        for (int ks = 0; ks < KSTEPS; ++ks)
#pragma unroll
          for (int j = 0; j < 8; ++j)
            insT(t5x[f], fabsf(bf2f_s(ahi[f][ks][j])));
      }
      // quad-butterfly merge -> full X top-T per sample
#pragma unroll
      for (int f = 0; f < 2; ++f) {
#pragma unroll
        for (int msk = 16; msk <= 32; msk <<= 1) {
          float o[T];
#pragma unroll
          for (int q = 0; q < T; ++q) o[q] = __shfl_xor(t5x[f][q], msk);
#pragma unroll
          for (int q = 0; q < T; ++q) insT(t5x[f], o[q]);
        }
      }
      if (lane < 16) {
#pragma unroll
        for (int f = 0; f < 2; ++f) {
          int slot = row * 64 + msub + f * 16 + l15;
#pragma unroll
          for (int q = 0; q < T; ++q) Xpool[slot * T + q] = t5x[f][q];
        }
      }
    }
    __syncthreads();   // s2: X region free -> B staging may begin

    // ---- Y chunks: stage B (P cols, transposed, bf16), MFMA, top-T
    float t5y[2][4][T];
#pragma unroll
    for (int f = 0; f < 2; ++f)
#pragma unroll
      for (int r = 0; r < 4; ++r)
#pragma unroll
        for (int q = 0; q < T; ++q) t5y[f][r][q] = 0.0f;

    for (int c = 0; c < NCH; ++c) {
      const int jb = c * 32;
      // stage: Bt[row][j][kk2], zero-padded
      for (int it2 = 0; it2 < KP / 8; ++it2) {
        int q = it2 * 256 + tid;
        int j = q & 31;
        int t = q >> 5;
        int rowq = t / (KP / 2);
        int kk2 = t - rowq * (KP / 2);
        int col = jb + j;
        int kk = 2 * kk2;
        const float* Pr = Pp + (size_t)(rowq ? b1 : b0) * 16384;
        float v0 = 0.0f, v1 = 0.0f;
        if (col < K) {
          if (kk < K)     v0 = Pr[kk * 128 + col];
          if (kk + 1 < K) v1 = Pr[(kk + 1) * 128 + col];
        }
        uint32_t h0 = f2bf(v0), h1 = f2bf(v1);
        ((uint32_t*)(sm + rowq * S_B))[j * BSTRU + kk2] = h0 | (h1 << 16);
      }
      __syncthreads();

      f32x4 acc[2][2];
#pragma unroll
      for (int f = 0; f < 2; ++f)
#pragma unroll
        for (int nf = 0; nf < 2; ++nf) acc[f][nf] = (f32x4){0.f, 0.f, 0.f, 0.f};

#pragma unroll
      for (int ks = 0; ks < KSTEPS; ++ks) {
        bf16x8 bh[2];
#pragma unroll
        for (int nf = 0; nf < 2; ++nf) {
          int uidx = (nf * 16 + l15) * BSTRU + ks * 16 + quad * 4;
          bh[nf] = *(const bf16x8*)(sm + row * S_B + uidx * 4);
        }
#pragma unroll
        for (int f = 0; f < 2; ++f)
#pragma unroll
          for (int nf = 0; nf < 2; ++nf)
            acc[f][nf] = __builtin_amdgcn_mfma_f32_16x16x32_bf16(ahi[f][ks], bh[nf], acc[f][nf], 0, 0, 0);
      }
#pragma unroll
      for (int f = 0; f < 2; ++f)
#pragma unroll
        for (int nf = 0; nf < 2; ++nf)
#pragma unroll
          for (int r = 0; r < 4; ++r)
            insT(t5y[f][r], fabsf(acc[f][nf][r]));
      __syncthreads();   // B region re-stageable
    }

    // ---- in-wave merge: full l15 butterfly + Xpool merge + hm + wave max
    float wmax = 0.0f;
#pragma unroll
    for (int f = 0; f < 2; ++f)
#pragma unroll
      for (int r = 0; r < 4; ++r) {
#pragma unroll
        for (int msk = 1; msk <= 8; msk <<= 1) {
          float o[T];
#pragma unroll
          for (int q = 0; q < T; ++q) o[q] = __shfl_xor(t5y[f][r][q], msk);
#pragma unroll
          for (int q = 0; q < T; ++q) insT(t5y[f][r], o[q]);
        }
        int slot = row * 64 + msub + f * 16 + quad * 4 + r;
        const float* xp = Xpool + slot * T;
#pragma unroll
        for (int q = 0; q < T; ++q) insT(t5y[f][r], xp[q]);
        float hm = t5y[f][r][0] / (t5y[f][r][T - 1] + 1e-9f);
        wmax = fmaxf(wmax, hm);
      }
    wmax = fmaxf(wmax, __shfl_xor(wmax, 16));
    wmax = fmaxf(wmax, __shfl_xor(wmax, 32));
    if (lane == 0) wvmax[wave] = wmax;
    __syncthreads();
    if (tid < 2)
      maxhm[tid] = fmaxf(maxhm[tid], fmaxf(wvmax[2 * tid], wvmax[2 * tid + 1]));
  }

  if (tid == 0) {
    float pen = fmaxf(maxhm[0] - yp[b0], 0.0f) + fmaxf(maxhm[1] - yp[b1], 0.0f);
    atomicAdd(&accum[0], pen);
    float d0 = log2f(fmaxf(yt[b0], 1e-9f)) - log2f(fmaxf(yp[b0], 1e-9f));
    float d1 = log2f(fmaxf(yt[b1], 1e-9f)) - log2f(fmaxf(yp[b1], 1e-9f));
    atomicAdd(&accum[1], fmaf(d0, d0, d1 * d1));
  }
}

struct ComboArgs {
  int ofs[4];
  uint32_t k0[4];
  uint32_t k1[4];
};

// max REGION (KP=128: 34816) + Xpool(128*5*4) + wvmax(16) + maxhm(8)
#define SM_BYTES (34816 + 2560 + 16 + 8)

__global__ __launch_bounds__(256)
__attribute__((amdgpu_waves_per_eu(4, 4)))
void viol_kernel(const float* __restrict__ Pp, const float* __restrict__ yp,
                 const float* __restrict__ yt, float* __restrict__ accum,
                 ComboArgs ca) {
  __shared__ __align__(16) char sm[SM_BYTES];
  int i = blockIdx.x >> 9;
  int rp = blockIdx.x & 511;
  switch (i) {
    case 0: process_combo< 80,  96, 3>(Pp, yp, yt, accum, ca.ofs[0], ca.k0[0], ca.k1[0], rp, sm); break;
    case 1: process_combo< 96,  96, 4>(Pp, yp, yt, accum, ca.ofs[1], ca.k0[1], ca.k1[1], rp, sm); break;
    case 2: process_combo<112, 128, 5>(Pp, yp, yt, accum, ca.ofs[2], ca.k0[2], ca.k1[2], rp, sm); break;
    default: process_combo<128, 128, 4>(Pp, yp, yt, accum, ca.ofs[3], ca.k0[3], ca.k1[3], rp, sm); break;
  }
}

__global__ void finalize_kernel(const float* __restrict__ accum, float* __restrict__ out) {
  if (threadIdx.x == 0 && blockIdx.x == 0) {
    float viol = accum[0] / 4096.0f;
    float lm = accum[1] / 4096.0f;
    out[0] = fmaf(0.5f, viol, lm);
    out[1] = lm;
    out[2] = viol;
  }
}

extern "C" void kernel_launch(void* const* d_in, const int* in_sizes, int n_in,
                              void* d_out, int out_size, void* d_ws, size_t ws_size,
                              hipStream_t stream) {
  const float* y_pred   = (const float*)d_in[0];
  const float* y_true   = (const float*)d_in[1];
  const float* P_padded = (const float*)d_in[2];
  float* accum = (float*)d_ws;
  float* out = (float*)d_out;

  hipMemsetAsync(accum, 0, 2 * sizeof(float), stream);

  // combos sorted as np.unique: (160,80,2)<-b%4==3, (192,96,3)<-1, (224,112,4)<-2, (256,128,3)<-0
  ComboArgs ca;
  const int ofs[4] = {3, 1, 2, 0};
  for (int i = 0; i < 4; ++i) {
    ca.ofs[i] = ofs[i];
    uint32_t o0, o1;
    tf2x32(0u, 42u, 0u, (uint32_t)i, o0, o1);  // fold_in(key(42), i)
    ca.k0[i] = o0;
    ca.k1[i] = o1;
  }

  viol_kernel<<<2048, 256, 0, stream>>>(P_padded, y_pred, y_true, accum, ca);
  finalize_kernel<<<1, 64, 0, stream>>>(accum, out);
}

// Round 5
// 554.890 us; speedup vs baseline: 2.3162x; 1.1064x over previous
//
#include <hip/hip_runtime.h>
#include <stdint.h>

typedef short bf16x8 __attribute__((ext_vector_type(8)));
typedef float f32x4 __attribute__((ext_vector_type(4)));

// ---------------------------------------------------------------------------
// Threefry-2x32 (JAX/Random123 schedule)
// ---------------------------------------------------------------------------
__host__ __device__ inline uint32_t rotl32(uint32_t v, int d) {
  return (v << d) | (v >> (32 - d));
}

__host__ __device__ inline void tf2x32(uint32_t k0, uint32_t k1,
                                       uint32_t x0, uint32_t x1,
                                       uint32_t& o0, uint32_t& o1) {
  uint32_t ks0 = k0, ks1 = k1, ks2 = k0 ^ k1 ^ 0x1BD11BDAu;
  x0 += ks0; x1 += ks1;
#define TF_R(r) { x0 += x1; x1 = rotl32(x1, (r)); x1 ^= x0; }
  TF_R(13) TF_R(15) TF_R(26) TF_R(6)
  x0 += ks1; x1 += ks2 + 1u;
  TF_R(17) TF_R(29) TF_R(16) TF_R(24)
  x0 += ks2; x1 += ks0 + 2u;
  TF_R(13) TF_R(15) TF_R(26) TF_R(6)
  x0 += ks0; x1 += ks1 + 3u;
  TF_R(17) TF_R(29) TF_R(16) TF_R(24)
  x0 += ks1; x1 += ks2 + 4u;
  TF_R(13) TF_R(15) TF_R(26) TF_R(6)
  x0 += ks2; x1 += ks0 + 5u;
#undef TF_R
  o0 = x0; o1 = x1;
}

// XLA's fp32 erf_inv (Giles polynomial); log1p via fast v_log path
__device__ __forceinline__ float erfinv_xla(float x) {
  float w = -__logf(fmaf(-x, x, 1.0f));
  float p;
  if (w < 5.0f) {
    w = w - 2.5f;
    p = 2.81022636e-08f;
    p = fmaf(p, w, 3.43273939e-07f);
    p = fmaf(p, w, -3.5233877e-06f);
    p = fmaf(p, w, -4.39150654e-06f);
    p = fmaf(p, w, 0.00021858087f);
    p = fmaf(p, w, -0.00125372503f);
    p = fmaf(p, w, -0.00417768164f);
    p = fmaf(p, w, 0.246640727f);
    p = fmaf(p, w, 1.50140941f);
  } else {
    w = sqrtf(w) - 3.0f;
    p = -0.000200214257f;
    p = fmaf(p, w, 0.000100950558f);
    p = fmaf(p, w, 0.00134934322f);
    p = fmaf(p, w, -0.00367342844f);
    p = fmaf(p, w, 0.00573950773f);
    p = fmaf(p, w, -0.0076224613f);
    p = fmaf(p, w, 0.00943887047f);
    p = fmaf(p, w, 1.00167406f);
    p = fmaf(p, w, 2.83297682f);
  }
  return p * x;
}

__device__ __forceinline__ float bits_to_normal(uint32_t bits) {
  uint32_t fb = (bits >> 9) | 0x3F800000u;
  float f = __uint_as_float(fb) - 1.0f;
  const float lo = -0.99999994f;
  float u = fmaf(f, 1.0f - lo, lo);
  u = fmaxf(lo, u);
  return 1.41421356f * erfinv_xla(u);
}

// bf16 RNE round
__device__ __forceinline__ uint32_t f2bf(float x) {
  uint32_t b = __float_as_uint(x);
  return (b + 0x7FFFu + ((b >> 16) & 1u)) >> 16;
}
__device__ __forceinline__ float bf2f_s(short h) {
  return __uint_as_float(((uint32_t)(uint16_t)h) << 16);
}

// branchless sorted-descending top-T insert
template <int T>
__device__ __forceinline__ void insT(float (&t)[T], float v) {
  float a = v;
#pragma unroll
  for (int q = 0; q < T; ++q) {
    float hi = fmaxf(t[q], a);
    a = fminf(t[q], a);
    t[q] = hi;
  }
}

// ---------------------------------------------------------------------------
// MFMA worker. Block = one combo row-pair (rp, rp+512). 2 sample-passes of 64.
// Pure-bf16 matmul (1 MFMA pass). Both rows' X resident in one LDS region;
// B staging reuses the region after A-frags are in registers. T = m+1.
// ---------------------------------------------------------------------------
template <int K, int KP, int T>
__device__ void process_combo(const float* __restrict__ Pp,
                              const float* __restrict__ yp,
                              const float* __restrict__ yt,
                              float* __restrict__ accum,
                              int ofs, uint32_t key0, uint32_t key1,
                              int rp, char* sm) {
  constexpr int KSTEPS = KP / 32;
  constexpr int NCH = (K + 31) / 32;
  constexpr int PH = K / 2;            // k-pairs per sample per row
  constexpr int ITERS = PH / 4;        // genX iters (64*PH/256)
  constexpr int XSTR = KP + 8;         // bf16 elems per sample row (+16B pad)
  constexpr int XSTRU = XSTR / 2;      // uints per sample row
  constexpr int XROW_U = 64 * XSTRU;   // uints per data-row section
  constexpr int BSTRU = KP / 2 + 4;    // uints per B col (+16B pad)
  constexpr int S_B = 32 * BSTRU * 4;  // bytes per B row-section
  constexpr int REGION = 2 * 64 * XSTR * 2;  // X both rows (>= 2*S_B)
  constexpr uint32_t HALF = 65536u * (uint32_t)K;

  const int tid = threadIdx.x;
  const int wave = tid >> 6;
  const int lane = tid & 63;
  const int quad = lane >> 4;
  const int l15 = lane & 15;
  const int row = wave >> 1;           // data-row of this wave (0/1)
  const int msub = (wave & 1) * 32;    // sample offset of this wave

  const int b0 = 4 * rp + ofs;
  const int b1 = 4 * (rp + 512) + ofs;

  uint32_t* Xu = (uint32_t*)sm;            // X both rows / B region
  float* Xpool = (float*)(sm + REGION);    // 128 * T floats
  float* wvmax = Xpool + 128 * T;          // 4 floats
  float* maxhm = wvmax + 4;                // 2 floats

  if (tid < 2) maxhm[tid] = 0.0f;

  for (int pass = 0; pass < 2; ++pass) {
    // ---- Phase A: generate X (both rows) straight to LDS as bf16
#pragma unroll
    for (int it = 0; it < ITERS; ++it) {
      int q = it * 256 + tid;
      int s_loc = q / PH;
      int k = 2 * (q - s_loc * PH);
      uint32_t ctr = (uint32_t)((rp * 128 + pass * 64 + s_loc) * K + k);
      uint32_t o0a, o1a, o0b, o1b;
      tf2x32(key0, key1, ctr, ctr + HALF, o0a, o1a);
      tf2x32(key0, key1, ctr + 1u, ctr + 1u + HALF, o0b, o1b);
      uint32_t idx = (uint32_t)(s_loc * XSTRU + (k >> 1));
      uint32_t h0 = f2bf(bits_to_normal(o0a));
      uint32_t h1 = f2bf(bits_to_normal(o0b));
      Xu[idx] = h0 | (h1 << 16);
      h0 = f2bf(bits_to_normal(o1a));
      h1 = f2bf(bits_to_normal(o1b));
      Xu[XROW_U + idx] = h0 | (h1 << 16);
    }
    if constexpr (KP > K) {   // zero-pad k in [K,KP) for both rows
      constexpr int PADU = (KP - K) / 2;
      for (int p = tid; p < 2 * 64 * PADU; p += 256) {
        int rs = p / PADU;
        int r = p - rs * PADU;
        Xu[rs * XSTRU + K / 2 + r] = 0;
      }
    }
    __syncthreads();   // s1: X visible

    // ---- A-frag load + X-col top-T -> Xpool
    bf16x8 ahi[2][KSTEPS];
#pragma unroll
    for (int f = 0; f < 2; ++f)
#pragma unroll
      for (int ks = 0; ks < KSTEPS; ++ks) {
        int off = ((row * 64 + msub + f * 16 + l15) * XSTR + ks * 32 + quad * 8) * 2;
        ahi[f][ks] = *(const bf16x8*)(sm + off);
      }
    {
      float t5x[2][T];
#pragma unroll
      for (int f = 0; f < 2; ++f) {
#pragma unroll
        for (int q = 0; q < T; ++q) t5x[f][q] = 0.0f;
#pragma unroll
        for (int ks = 0; ks < KSTEPS; ++ks)
#pragma unroll
          for (int j = 0; j < 8; ++j)
            insT(t5x[f], fabsf(bf2f_s(ahi[f][ks][j])));
      }
      // quad-butterfly merge -> full X top-T per sample
#pragma unroll
      for (int f = 0; f < 2; ++f) {
#pragma unroll
        for (int msk = 16; msk <= 32; msk <<= 1) {
          float o[T];
#pragma unroll
          for (int q = 0; q < T; ++q) o[q] = __shfl_xor(t5x[f][q], msk);
#pragma unroll
          for (int q = 0; q < T; ++q) insT(t5x[f], o[q]);
        }
      }
      if (lane < 16) {
#pragma unroll
        for (int f = 0; f < 2; ++f) {
          int slot = row * 64 + msub + f * 16 + l15;
#pragma unroll
          for (int q = 0; q < T; ++q) Xpool[slot * T + q] = t5x[f][q];
        }
      }
    }
    __syncthreads();   // s2: X region free -> B staging may begin

    // ---- Y chunks: stage B (P cols, transposed, bf16), MFMA, top-T
    float t5y[2][4][T];
#pragma unroll
    for (int f = 0; f < 2; ++f)
#pragma unroll
      for (int r = 0; r < 4; ++r)
#pragma unroll
        for (int q = 0; q < T; ++q) t5y[f][r][q] = 0.0f;

    for (int c = 0; c < NCH; ++c) {
      const int jb = c * 32;
      // stage: Bt[row][j][kk2], zero-padded
      for (int it2 = 0; it2 < KP / 8; ++it2) {
        int q = it2 * 256 + tid;
        int j = q & 31;
        int t = q >> 5;
        int rowq = t / (KP / 2);
        int kk2 = t - rowq * (KP / 2);
        int col = jb + j;
        int kk = 2 * kk2;
        const float* Pr = Pp + (size_t)(rowq ? b1 : b0) * 16384;
        float v0 = 0.0f, v1 = 0.0f;
        if (col < K) {
          if (kk < K)     v0 = Pr[kk * 128 + col];
          if (kk + 1 < K) v1 = Pr[(kk + 1) * 128 + col];
        }
        uint32_t h0 = f2bf(v0), h1 = f2bf(v1);
        ((uint32_t*)(sm + rowq * S_B))[j * BSTRU + kk2] = h0 | (h1 << 16);
      }
      __syncthreads();

      f32x4 acc[2][2];
#pragma unroll
      for (int f = 0; f < 2; ++f)
#pragma unroll
        for (int nf = 0; nf < 2; ++nf) acc[f][nf] = (f32x4){0.f, 0.f, 0.f, 0.f};

#pragma unroll
      for (int ks = 0; ks < KSTEPS; ++ks) {
        bf16x8 bh[2];
#pragma unroll
        for (int nf = 0; nf < 2; ++nf) {
          int uidx = (nf * 16 + l15) * BSTRU + ks * 16 + quad * 4;
          bh[nf] = *(const bf16x8*)(sm + row * S_B + uidx * 4);
        }
#pragma unroll
        for (int f = 0; f < 2; ++f)
#pragma unroll
          for (int nf = 0; nf < 2; ++nf)
            acc[f][nf] = __builtin_amdgcn_mfma_f32_16x16x32_bf16(ahi[f][ks], bh[nf], acc[f][nf], 0, 0, 0);
      }
#pragma unroll
      for (int f = 0; f < 2; ++f)
#pragma unroll
        for (int nf = 0; nf < 2; ++nf)
#pragma unroll
          for (int r = 0; r < 4; ++r)
            insT(t5y[f][r], fabsf(acc[f][nf][r]));
      __syncthreads();   // B region re-stageable
    }

    // ---- in-wave merge: full l15 butterfly + Xpool merge + hm + wave max
    float wmax = 0.0f;
#pragma unroll
    for (int f = 0; f < 2; ++f)
#pragma unroll
      for (int r = 0; r < 4; ++r) {
#pragma unroll
        for (int msk = 1; msk <= 8; msk <<= 1) {
          float o[T];
#pragma unroll
          for (int q = 0; q < T; ++q) o[q] = __shfl_xor(t5y[f][r][q], msk);
#pragma unroll
          for (int q = 0; q < T; ++q) insT(t5y[f][r], o[q]);
        }
        int slot = row * 64 + msub + f * 16 + quad * 4 + r;
        const float* xp = Xpool + slot * T;
#pragma unroll
        for (int q = 0; q < T; ++q) insT(t5y[f][r], xp[q]);
        float hm = t5y[f][r][0] / (t5y[f][r][T - 1] + 1e-9f);
        wmax = fmaxf(wmax, hm);
      }
    wmax = fmaxf(wmax, __shfl_xor(wmax, 16));
    wmax = fmaxf(wmax, __shfl_xor(wmax, 32));
    if (lane == 0) wvmax[wave] = wmax;
    __syncthreads();
    if (tid < 2)
      maxhm[tid] = fmaxf(maxhm[tid], fmaxf(wvmax[2 * tid], wvmax[2 * tid + 1]));
  }

  if (tid == 0) {
    float pen = fmaxf(maxhm[0] - yp[b0], 0.0f) + fmaxf(maxhm[1] - yp[b1], 0.0f);
    atomicAdd(&accum[0], pen);
    float d0 = log2f(fmaxf(yt[b0], 1e-9f)) - log2f(fmaxf(yp[b0], 1e-9f));
    float d1 = log2f(fmaxf(yt[b1], 1e-9f)) - log2f(fmaxf(yp[b1], 1e-9f));
    atomicAdd(&accum[1], fmaf(d0, d0, d1 * d1));
  }
}

struct ComboArgs {
  int ofs[4];
  uint32_t k0[4];
  uint32_t k1[4];
};

// max REGION (KP=128: 34816) + Xpool(128*5*4) + wvmax(16) + maxhm(8)
#define SM_BYTES (34816 + 2560 + 16 + 8)

// (256,2): VGPR cap 256 -> compiler picks 128, matching the LDS-imposed
// 4 blocks/CU (4 waves/EU). (256,4)/waves_per_eu(4,4) forced 64 VGPR + spills.
__global__ __launch_bounds__(256, 2)
void viol_kernel(const float* __restrict__ Pp, const float* __restrict__ yp,
                 const float* __restrict__ yt, float* __restrict__ accum,
                 ComboArgs ca) {
  __shared__ __align__(16) char sm[SM_BYTES];
  int i = blockIdx.x >> 9;
  int rp = blockIdx.x & 511;
  switch (i) {
    case 0: process_combo< 80,  96, 3>(Pp, yp, yt, accum, ca.ofs[0], ca.k0[0], ca.k1[0], rp, sm); break;
    case 1: process_combo< 96,  96, 4>(Pp, yp, yt, accum, ca.ofs[1], ca.k0[1], ca.k1[1], rp, sm); break;
    case 2: process_combo<112, 128, 5>(Pp, yp, yt, accum, ca.ofs[2], ca.k0[2], ca.k1[2], rp, sm); break;
    default: process_combo<128, 128, 4>(Pp, yp, yt, accum, ca.ofs[3], ca.k0[3], ca.k1[3], rp, sm); break;
  }
}

__global__ void finalize_kernel(const float* __restrict__ accum, float* __restrict__ out) {
  if (threadIdx.x == 0 && blockIdx.x == 0) {
    float viol = accum[0] / 4096.0f;
    float lm = accum[1] / 4096.0f;
    out[0] = fmaf(0.5f, viol, lm);
    out[1] = lm;
    out[2] = viol;
  }
}

extern "C" void kernel_launch(void* const* d_in, const int* in_sizes, int n_in,
                              void* d_out, int out_size, void* d_ws, size_t ws_size,
                              hipStream_t stream) {
  const float* y_pred   = (const float*)d_in[0];
  const float* y_true   = (const float*)d_in[1];
  const float* P_padded = (const float*)d_in[2];
  float* accum = (float*)d_ws;
  float* out = (float*)d_out;

  hipMemsetAsync(accum, 0, 2 * sizeof(float), stream);

  // combos sorted as np.unique: (160,80,2)<-b%4==3, (192,96,3)<-1, (224,112,4)<-2, (256,128,3)<-0
  ComboArgs ca;
  const int ofs[4] = {3, 1, 2, 0};
  for (int i = 0; i < 4; ++i) {
    ca.ofs[i] = ofs[i];
    uint32_t o0, o1;
    tf2x32(0u, 42u, 0u, (uint32_t)i, o0, o1);  // fold_in(key(42), i)
    ca.k0[i] = o0;
    ca.k1[i] = o1;
  }

  viol_kernel<<<2048, 256, 0, stream>>>(P_padded, y_pred, y_true, accum, ca);
  finalize_kernel<<<1, 64, 0, stream>>>(accum, out);
}